// Round 4
// baseline (236.959 us; speedup 1.0000x reference)
//
#include <hip/hip_runtime.h>
#include <hip/hip_bf16.h>

// SatelliteSpecificNormalization:
//   x: (B=16, N=8, C=1, H=512, W=512) f32, sids (B,N) in [-1,8),
//   weight/bias (8,) f32.  out = valid ? x*w[sid]+b[sid] : x
//
// R1 diagnosis: 2.5 TB/s @ 80us -- latency-bound (1 load in flight/thread,
// VGPR=8). Fix: ILP-4 unroll (4 independent coalesced 16B loads issued
// back-to-back), exact grid, nontemporal stores to keep output from
// evicting L3-resident input (harness restore leaves x warm in L3).
// R3 fix: __builtin_nontemporal_store needs a clang ext_vector type,
// not HIP's struct float4.

typedef float floatx4 __attribute__((ext_vector_type(4)));

#define NUM_SLABS 128          // B*N
#define LOG2_VEC_PER_SLAB 16   // (C*H*W)/4 = 65536 float4 per slab
#define ILP 4

__global__ __launch_bounds__(256) void sat_norm_kernel(
    const floatx4* __restrict__ x,
    const int* __restrict__ sids,
    const float* __restrict__ weight,
    const float* __restrict__ bias,
    floatx4* __restrict__ out,
    int n_vec) {
    __shared__ float s_w[NUM_SLABS];
    __shared__ float s_b[NUM_SLABS];
    const int t = threadIdx.x;
    if (t < NUM_SLABS) {
        const int sid = sids[t];
        const bool valid = sid >= 0;
        const int idx = valid ? sid : 0;
        s_w[t] = valid ? weight[idx] : 1.0f;
        s_b[t] = valid ? bias[idx] : 0.0f;
    }
    __syncthreads();

    const int base = blockIdx.x * (blockDim.x * ILP) + t;

    // Issue all ILP loads first (independent, coalesced within each wave).
    floatx4 xv[ILP];
    int     v[ILP];
#pragma unroll
    for (int k = 0; k < ILP; ++k) {
        v[k] = base + k * 256;
        if (v[k] < n_vec) xv[k] = x[v[k]];
    }
#pragma unroll
    for (int k = 0; k < ILP; ++k) {
        if (v[k] < n_vec) {
            const int slab = v[k] >> LOG2_VEC_PER_SLAB;   // wave-uniform (broadcast)
            const float w = s_w[slab];
            const float b = s_b[slab];
            floatx4 ov;
            ov.x = fmaf(xv[k].x, w, b);
            ov.y = fmaf(xv[k].y, w, b);
            ov.z = fmaf(xv[k].z, w, b);
            ov.w = fmaf(xv[k].w, w, b);
            __builtin_nontemporal_store(ov, &out[v[k]]);
        }
    }
}

extern "C" void kernel_launch(void* const* d_in, const int* in_sizes, int n_in,
                              void* d_out, int out_size, void* d_ws, size_t ws_size,
                              hipStream_t stream) {
    const floatx4* x     = (const floatx4*)d_in[0];
    const int*    sids   = (const int*)d_in[1];
    const float*  weight = (const float*)d_in[2];
    const float*  bias   = (const float*)d_in[3];
    floatx4* out = (floatx4*)d_out;

    const int n_vec = out_size / 4;                  // 8,388,608 float4s
    const int block = 256;
    const int per_block = block * ILP;               // 1024 float4s/block
    const int blocks = (n_vec + per_block - 1) / per_block;   // 8192
    sat_norm_kernel<<<blocks, block, 0, stream>>>(x, sids, weight, bias, out, n_vec);
}